// Round 1
// baseline (97.496 us; speedup 1.0000x reference)
//
#include <hip/hip_runtime.h>
#include <math.h>
#include <float.h>

#define B_ 64
#define T_ 100
#define N_ 20000
#define NQ (B_ * T_)              // 6400 queries
#define NP2 (N_ / 2)              // 10000 point pairs
#define NG8 (N_ / 8)              // 2500 groups of 8 points
#define NSL 5                     // point slices per query-group
#define WPB 4                     // waves per block in k_nn
#define GPW (NG8 / (NSL * WPB))   // 125 groups per wave

typedef float f2 __attribute__((ext_vector_type(2)));
typedef float f4 __attribute__((ext_vector_type(4)));
typedef unsigned long long u64;

// ws layout:
//   [0, 51200)        keys u64[NQ]  (packed sortable(e)<<32 | idx, atomicMin)
//   [51200, 371200)   prep f4[2*NP2]: per pair {-2x0,-2x1,-2y0,-2y1},
//                                              {-2z0,-2z1, p2_0, p2_1}
#define KEYS_OFF 0
#define PREP_OFF (NQ * 8)

// Map f32 -> u32 preserving < order for all finite values (incl. negatives).
__device__ __forceinline__ unsigned int f32_sortable(float f) {
    unsigned int u = __float_as_uint(f);
    return ((int)u >= 0) ? (u | 0x80000000u) : ~u;
}

// e = p2 - 2 q.g for 2 points, FMA nesting identical to the verified kernel:
// fma(mx, qx, fma(my, qy, fma(mz, qz, p2)))
__device__ __forceinline__ f2 edist2(f4 A, f4 Bv, f2 vx, f2 vy, f2 vz) {
    f2 mx = { A.x,  A.y  }, my = { A.z,  A.w  };
    f2 mz = { Bv.x, Bv.y }, p2 = { Bv.z, Bv.w };
    return __builtin_elementwise_fma(mx, vx,
           __builtin_elementwise_fma(my, vy,
           __builtin_elementwise_fma(mz, vz, p2)));
}

// ---------------------------------------------------------------------------
// Kernel 1: prep. One launch replaces 2500 per-block LDS stagings:
// precompute (-2g, |g|^2) pair-packed, init keys to +inf, zero out.
// ---------------------------------------------------------------------------
__global__ __launch_bounds__(256) void k_prep(
    const float* __restrict__ boundary,   // [4,N]
    f4* __restrict__ prep,
    u64* __restrict__ keys,
    float* __restrict__ out)
{
    const int t = blockIdx.x * 256 + threadIdx.x;   // grid 40*256 = 10240
    if (t < NP2) {
        const int n0 = 2 * t;
        const float x0 = boundary[n0],          x1 = boundary[n0 + 1];
        const float y0 = boundary[N_ + n0],     y1 = boundary[N_ + n0 + 1];
        const float z0 = boundary[2 * N_ + n0], z1 = boundary[2 * N_ + n0 + 1];
        f4 a = { -2.f * x0, -2.f * x1, -2.f * y0, -2.f * y1 };
        f4 b = { -2.f * z0, -2.f * z1,
                 x0 * x0 + y0 * y0 + z0 * z0,
                 x1 * x1 + y1 * y1 + z1 * z1 };
        prep[2 * t]     = a;
        prep[2 * t + 1] = b;
    }
    if (t < NQ) keys[t] = ~0ull;
    if (t == 0) out[0] = 0.0f;
}

// ---------------------------------------------------------------------------
// Kernel 2: NN, one query per lane, broadcast point data.
// Rigid transforms preserve distance, so the search runs in the global frame:
// q = R w + t, e = |g|^2 - 2 q.g (argmin-equivalent to |q-g|^2).
// No LDS, no __syncthreads: all lanes of a wave read the SAME prep addresses
// (wave-uniform loop index -> broadcast / scalarizable loads).
// Grid = 100 query-groups x NSL point slices; block = 4 waves, each wave
// covers GPW groups of 8 points. One u64 atomicMin per (lane, wave).
// ---------------------------------------------------------------------------
__global__ __launch_bounds__(256) void k_nn(
    const float* __restrict__ poses,      // [B,4,4]
    const float* __restrict__ wpts,       // [B,T,3]
    const f4* __restrict__ prep,
    u64* __restrict__ keys)               // [NQ]
{
    const int qg   = blockIdx.x / NSL;
    const int sl   = blockIdx.x - qg * NSL;
    const int lane = threadIdx.x & 63;
    const int wv   = __builtin_amdgcn_readfirstlane((int)(threadIdx.x >> 6));

    // ---- per-lane query: global waypoint q = R w + t ----
    const int i = qg * 64 + lane;
    const int b = i / T_;
    const float* P = poses + b * 16;
    const float* W = wpts + i * 3;
    const float wx = W[0], wy = W[1], wz = W[2];
    const float qx = P[0] * wx + P[1] * wy + P[2]  * wz + P[3];
    const float qy = P[4] * wx + P[5] * wy + P[6]  * wz + P[7];
    const float qz = P[8] * wx + P[9] * wy + P[10] * wz + P[11];
    const f2 vx = { qx, qx }, vy = { qy, qy }, vz = { qz, qz };

    const int g0 = (sl * WPB + wv) * GPW;

    float best = FLT_MAX;
    int   bg   = g0;

#pragma unroll 5
    for (int g = g0; g < g0 + GPW; ++g) {
        const f4* p8 = prep + 8 * g;      // 128 B, contiguous, wave-uniform
        const f4 A0 = p8[0], B0 = p8[1], A1 = p8[2], B1 = p8[3];
        const f4 A2 = p8[4], B2 = p8[5], A3 = p8[6], B3 = p8[7];

        const f2 e0 = edist2(A0, B0, vx, vy, vz);
        const f2 e1 = edist2(A1, B1, vx, vy, vz);
        const f2 e2 = edist2(A2, B2, vx, vy, vz);
        const f2 e3 = edist2(A3, B3, vx, vy, vz);

        const f2 m01 = __builtin_elementwise_min(e0, e1);
        const f2 m23 = __builtin_elementwise_min(e2, e3);
        const f2 m   = __builtin_elementwise_min(m01, m23);
        const float s = fminf(m.x, m.y);
        if (s < best) { best = s; bg = g; }
    }

    // ---- resolve exact index inside winning group (identical FMA math) ----
    {
        const f4* p8 = prep + 8 * bg;
        const f4 A0 = p8[0], B0 = p8[1], A1 = p8[2], B1 = p8[3];
        const f4 A2 = p8[4], B2 = p8[5], A3 = p8[6], B3 = p8[7];
        const f2 e0 = edist2(A0, B0, vx, vy, vz);
        const f2 e1 = edist2(A1, B1, vx, vy, vz);
        const f2 e2 = edist2(A2, B2, vx, vy, vz);
        const f2 e3 = edist2(A3, B3, vx, vy, vz);
        const int loc = 8 * bg;
        int li = (e0.x == best) ? loc
               : (e0.y == best) ? loc + 1
               : (e1.x == best) ? loc + 2
               : (e1.y == best) ? loc + 3
               : (e2.x == best) ? loc + 4
               : (e2.y == best) ? loc + 5
               : (e3.x == best) ? loc + 6 : loc + 7;
        u64 key = ((u64)f32_sortable(best) << 32) | (unsigned)li;
        atomicMin(&keys[i], key);
    }
}

// ---------------------------------------------------------------------------
// Kernel 3: per query, unpack winning index, global-frame epilogue:
// dots = (q - g) . n (rotation-invariant), ExpRelu, block-reduce, atomicAdd.
// ---------------------------------------------------------------------------
__global__ __launch_bounds__(256) void k_epilogue(
    const float* __restrict__ poses,
    const float* __restrict__ wpts,
    const float* __restrict__ boundary,   // [4,N]
    const float* __restrict__ bnorm,      // [3,N]
    const u64* __restrict__ keys,
    float* __restrict__ out)
{
    const int tid = threadIdx.x;
    const int i = blockIdx.x * 256 + tid;     // grid = 25 -> i in [0,6400)

    const int bi = (int)(unsigned)(keys[i] & 0xFFFFFFFFull);

    const int b = i / T_;
    const float* P = poses + b * 16;
    const float* W = wpts + i * 3;
    const float wx = W[0], wy = W[1], wz = W[2];
    const float qx = P[0] * wx + P[1] * wy + P[2]  * wz + P[3];
    const float qy = P[4] * wx + P[5] * wy + P[6]  * wz + P[7];
    const float qz = P[8] * wx + P[9] * wy + P[10] * wz + P[11];

    const float gx = boundary[bi], gy = boundary[N_ + bi], gz = boundary[2 * N_ + bi];
    const float nx = bnorm[bi],    ny = bnorm[N_ + bi],    nz = bnorm[2 * N_ + bi];

    const float dots = (qx - gx) * nx + (qy - gy) * ny + (qz - gz) * nz;
    // ExpRelu: alpha=1, beta=0.5; pre-scaled for the final mean
    float val = (dots > 0.0f) ? (dots + 1.0f) : expf(0.5f * dots);
    val *= (1.0f / (float)NQ);

    __shared__ float red[256];
    red[tid] = val;
    __syncthreads();
#pragma unroll
    for (int s = 128; s > 0; s >>= 1) {
        if (tid < s) red[tid] += red[tid + s];
        __syncthreads();
    }
    if (tid == 0) atomicAdd(out, red[0]);
}

extern "C" void kernel_launch(void* const* d_in, const int* in_sizes, int n_in,
                              void* d_out, int out_size, void* d_ws, size_t ws_size,
                              hipStream_t stream) {
    const float* poses    = (const float*)d_in[0];
    const float* wpts     = (const float*)d_in[1];
    const float* boundary = (const float*)d_in[2];
    const float* bnorm    = (const float*)d_in[3];
    float* out = (float*)d_out;

    u64* keys = (u64*)((char*)d_ws + KEYS_OFF);
    f4*  prep = (f4*)((char*)d_ws + PREP_OFF);

    k_prep<<<40, 256, 0, stream>>>(boundary, prep, keys, out);
    k_nn<<<100 * NSL, 256, 0, stream>>>(poses, wpts, prep, keys);
    k_epilogue<<<NQ / 256, 256, 0, stream>>>(
        poses, wpts, boundary, bnorm, keys, out);
}

// Round 2
// 80.182 us; speedup vs baseline: 1.2159x; 1.2159x over previous
//
#include <hip/hip_runtime.h>
#include <math.h>
#include <float.h>

#define B_ 64
#define T_ 100
#define N_ 20000
#define NQ (B_ * T_)              // 6400 queries
#define QG 256                    // queries per group = one wave (4 per lane)
#define NQG (NQ / QG)             // 25 query groups
#define PTB 400                   // points per block (4 waves x 100)
#define PPB (PTB / 2)             // 200 point-pairs per block
#define BPQ (N_ / PTB)            // 50 point-slices = blocks per query group
#define GPW 25                    // groups of 4 points per wave

typedef float f2 __attribute__((ext_vector_type(2)));
typedef float f4 __attribute__((ext_vector_type(4)));
typedef unsigned long long u64;

// ws layout: u64 partial[BPQ][NQ]  (50 * 6400 * 8 = 2.56 MB)
// Every slot is written by its owning block -> no init pass, no atomics.
#define PART_OFF 0

// Map f32 -> u32 preserving < order for all finite values (incl. negatives).
__device__ __forceinline__ unsigned int f32_sortable(float f) {
    unsigned int u = __float_as_uint(f);
    return ((int)u >= 0) ? (u | 0x80000000u) : ~u;
}

// e = p2 - 2 q.g for a point-PAIR, FMA nesting identical to the verified
// kernels: fma(mx, qx, fma(my, qy, fma(mz, qz, p2)))
__device__ __forceinline__ f2 edist2(f4 A, f4 Bv, f2 vx, f2 vy, f2 vz) {
    f2 mx = { A.x,  A.y  }, my = { A.z,  A.w  };
    f2 mz = { Bv.x, Bv.y }, p2 = { Bv.z, Bv.w };
    return __builtin_elementwise_fma(mx, vx,
           __builtin_elementwise_fma(my, vy,
           __builtin_elementwise_fma(mz, vz, p2)));
}

// ---------------------------------------------------------------------------
// Kernel 1: NN. Block = (query-group of 256, point-slice of 400).
// Rigid transforms preserve distance, so the search runs in the global
// frame: q = R w + t, e = |g|^2 - 2 q.g (argmin-equivalent to |q-g|^2).
// Each LANE owns 4 queries (hoisted f2 splats); each WAVE covers all 256
// queries of the group x its 100-point sub-slice via uniform (broadcast,
// conflict-free) LDS reads -> one staged f4 feeds 256 q.p pairs.
// Per block: 4 waves' per-query keys are min-reduced through LDS and one
// u64 per query lands in partial[slice][query]. No atomics, no init.
// ---------------------------------------------------------------------------
__global__ __launch_bounds__(256, 4) void k_nn(
    const float* __restrict__ poses,      // [B,4,4]
    const float* __restrict__ wpts,       // [B,T,3]
    const float* __restrict__ boundary,   // [4,N]
    u64* __restrict__ partial,            // [BPQ][NQ]
    float* __restrict__ out)
{
    __shared__ f4 sh[PPB][2];             // pair-packed points, 6.4 KB
    __shared__ u64 red[4 * 256];          // cross-wave key reduce, 8 KB

    const int bx   = blockIdx.x;
    const int qg   = bx / BPQ;
    const int bsl  = bx - qg * BPQ;
    const int tid  = threadIdx.x;
    const int lane = tid & 63;
    const int wv   = tid >> 6;
    const int pbase = bsl * PTB;

    // out is consumed by k_epilogue (next dispatch) via atomicAdd; zero here.
    if (bx == 0 && tid == 0) out[0] = 0.0f;

    // ---- stage slice: (-2g, |g|^2) pair-packed (identical arithmetic) ----
    for (int pp = tid; pp < PPB; pp += 256) {
        const int n0 = pbase + 2 * pp;
        const float x0 = boundary[n0],          x1 = boundary[n0 + 1];
        const float y0 = boundary[N_ + n0],     y1 = boundary[N_ + n0 + 1];
        const float z0 = boundary[2 * N_ + n0], z1 = boundary[2 * N_ + n0 + 1];
        f4 a = { -2.f * x0, -2.f * x1, -2.f * y0, -2.f * y1 };
        f4 b = { -2.f * z0, -2.f * z1,
                 x0 * x0 + y0 * y0 + z0 * z0,
                 x1 * x1 + y1 * y1 + z1 * z1 };
        sh[pp][0] = a;
        sh[pp][1] = b;
    }

    // ---- 4 queries per lane: global waypoint q = R w + t, splats hoisted --
    f2 vx[4], vy[4], vz[4];
#pragma unroll
    for (int s = 0; s < 4; ++s) {
        const int i = qg * QG + s * 64 + lane;
        const int b = i / T_;
        const float* P = poses + b * 16;
        const float* W = wpts + i * 3;
        const float wx = W[0], wy = W[1], wz = W[2];
        const float qxx = P[0] * wx + P[1] * wy + P[2]  * wz + P[3];
        const float qyy = P[4] * wx + P[5] * wy + P[6]  * wz + P[7];
        const float qzz = P[8] * wx + P[9] * wy + P[10] * wz + P[11];
        vx[s] = (f2){ qxx, qxx };
        vy[s] = (f2){ qyy, qyy };
        vz[s] = (f2){ qzz, qzz };
    }
    __syncthreads();

    const int prbase = wv * (PPB / 4);    // wave's pair base (wv*50)

    float best[4] = { FLT_MAX, FLT_MAX, FLT_MAX, FLT_MAX };
    int   bg[4]   = { 0, 0, 0, 0 };

#pragma unroll 5
    for (int g = 0; g < GPW; ++g) {
        const int pr = prbase + 2 * g;
        const f4 A0 = sh[pr][0],     B0 = sh[pr][1];
        const f4 A1 = sh[pr + 1][0], B1 = sh[pr + 1][1];
#pragma unroll
        for (int s = 0; s < 4; ++s) {
            const f2 e01 = edist2(A0, B0, vx[s], vy[s], vz[s]);
            const f2 e23 = edist2(A1, B1, vx[s], vy[s], vz[s]);
            const f2 m   = __builtin_elementwise_min(e01, e23);
            const float sc = fminf(m.x, m.y);
            bg[s]   = (sc < best[s]) ? g : bg[s];
            best[s] = fminf(sc, best[s]);
        }
    }

    // ---- resolve exact index inside winning group (identical FMA math) ----
#pragma unroll
    for (int s = 0; s < 4; ++s) {
        const int pr = prbase + 2 * bg[s];
        const f4 A0 = sh[pr][0],     B0 = sh[pr][1];
        const f4 A1 = sh[pr + 1][0], B1 = sh[pr + 1][1];
        const f2 e01 = edist2(A0, B0, vx[s], vy[s], vz[s]);
        const f2 e23 = edist2(A1, B1, vx[s], vy[s], vz[s]);
        const int base_i = pbase + wv * 100 + 4 * bg[s];
        const int li = (e01.x == best[s]) ? base_i
                     : (e01.y == best[s]) ? base_i + 1
                     : (e23.x == best[s]) ? base_i + 2 : base_i + 3;
        red[wv * 256 + s * 64 + lane] =
            ((u64)f32_sortable(best[s]) << 32) | (unsigned)li;
    }
    __syncthreads();

    // ---- cross-wave min (4 slices of the block) -> one u64 per query ----
    {
        const u64 a = red[tid],       b = red[256 + tid];
        const u64 c = red[512 + tid], d = red[768 + tid];
        const u64 m0 = a < b ? a : b;
        const u64 m1 = c < d ? c : d;
        partial[bsl * NQ + qg * QG + tid] = m0 < m1 ? m0 : m1;
    }
}

// ---------------------------------------------------------------------------
// Kernel 2: per query, min over the 50 slice-partials (coalesced), unpack
// winning index, global-frame epilogue: dots = (q - g) . n (rotation-
// invariant == reference's local-frame dot), ExpRelu, block-reduce, atomicAdd.
// ---------------------------------------------------------------------------
__global__ __launch_bounds__(256) void k_epilogue(
    const float* __restrict__ poses,
    const float* __restrict__ wpts,
    const float* __restrict__ boundary,   // [4,N]
    const float* __restrict__ bnorm,      // [3,N]
    const u64* __restrict__ partial,
    float* __restrict__ out)
{
    const int tid = threadIdx.x;
    const int i = blockIdx.x * 256 + tid;     // grid = 25 -> i in [0,6400)

    u64 best = ~0ull;
#pragma unroll 10
    for (int sl = 0; sl < BPQ; ++sl) {
        const u64 k = partial[sl * NQ + i];
        best = k < best ? k : best;
    }
    const int bi = (int)(unsigned)(best & 0xFFFFFFFFull);

    const int b = i / T_;
    const float* P = poses + b * 16;
    const float* W = wpts + i * 3;
    const float wx = W[0], wy = W[1], wz = W[2];
    const float qx = P[0] * wx + P[1] * wy + P[2]  * wz + P[3];
    const float qy = P[4] * wx + P[5] * wy + P[6]  * wz + P[7];
    const float qz = P[8] * wx + P[9] * wy + P[10] * wz + P[11];

    const float gx = boundary[bi], gy = boundary[N_ + bi], gz = boundary[2 * N_ + bi];
    const float nx = bnorm[bi],    ny = bnorm[N_ + bi],    nz = bnorm[2 * N_ + bi];

    const float dots = (qx - gx) * nx + (qy - gy) * ny + (qz - gz) * nz;
    // ExpRelu: alpha=1, beta=0.5; pre-scaled for the final mean
    float val = (dots > 0.0f) ? (dots + 1.0f) : expf(0.5f * dots);
    val *= (1.0f / (float)NQ);

    __shared__ float redf[256];
    redf[tid] = val;
    __syncthreads();
#pragma unroll
    for (int s = 128; s > 0; s >>= 1) {
        if (tid < s) redf[tid] += redf[tid + s];
        __syncthreads();
    }
    if (tid == 0) atomicAdd(out, redf[0]);
}

extern "C" void kernel_launch(void* const* d_in, const int* in_sizes, int n_in,
                              void* d_out, int out_size, void* d_ws, size_t ws_size,
                              hipStream_t stream) {
    const float* poses    = (const float*)d_in[0];
    const float* wpts     = (const float*)d_in[1];
    const float* boundary = (const float*)d_in[2];
    const float* bnorm    = (const float*)d_in[3];
    float* out = (float*)d_out;

    u64* partial = (u64*)((char*)d_ws + PART_OFF);

    k_nn<<<NQG * BPQ, 256, 0, stream>>>(poses, wpts, boundary, partial, out);
    k_epilogue<<<NQ / 256, 256, 0, stream>>>(
        poses, wpts, boundary, bnorm, partial, out);
}

// Round 3
// 78.909 us; speedup vs baseline: 1.2355x; 1.0161x over previous
//
#include <hip/hip_runtime.h>
#include <math.h>
#include <float.h>

#define B_ 64
#define T_ 100
#define N_ 20000
#define NQ (B_ * T_)              // 6400 queries
#define QG 256                    // queries per group = one block (4 per lane)
#define NQG (NQ / QG)             // 25 query groups
#define PTB 400                   // points per block (4 waves x 100)
#define PPB (PTB / 2)             // 200 point-pairs per block
#define BPQ (N_ / PTB)            // 50 point-slices = blocks per query group
#define GPW 25                    // groups of 4 points per wave
#define EPI_T 128                 // k_epilogue block size (grid 50)

typedef float f2 __attribute__((ext_vector_type(2)));
typedef float f4 __attribute__((ext_vector_type(4)));
typedef unsigned long long u64;

// ws layout: u64 partial[BPQ][NQ]  (50 * 6400 * 8 = 2.56 MB)
// Every slot is written by its owning block -> no init pass, no atomics.
#define PART_OFF 0

// Map f32 -> u32 preserving < order for all finite values (incl. negatives).
__device__ __forceinline__ unsigned int f32_sortable(float f) {
    unsigned int u = __float_as_uint(f);
    return ((int)u >= 0) ? (u | 0x80000000u) : ~u;
}

// e = p2 - 2 q.g for a point-PAIR, FMA nesting identical to the verified
// kernels: fma(mx, qx, fma(my, qy, fma(mz, qz, p2)))
__device__ __forceinline__ f2 edist2(f4 A, f4 Bv, f2 vx, f2 vy, f2 vz) {
    f2 mx = { A.x,  A.y  }, my = { A.z,  A.w  };
    f2 mz = { Bv.x, Bv.y }, p2 = { Bv.z, Bv.w };
    return __builtin_elementwise_fma(mx, vx,
           __builtin_elementwise_fma(my, vy,
           __builtin_elementwise_fma(mz, vz, p2)));
}

// ---------------------------------------------------------------------------
// Kernel 1: NN. Block = (query-group of 256, point-slice of 400).
// Rigid transforms preserve distance, so the search runs in the global
// frame: q = R w + t, e = |g|^2 - 2 q.g (argmin-equivalent to |q-g|^2).
// Query sharing: each THREAD computes one query (bit-identical expression)
// and publishes it through SoA LDS -> 12 broadcast ds_read_b32 per lane
// replaces 48 scattered VMEM loads per wave (50x redundancy removed).
// Each LANE owns 4 queries; each WAVE covers all 256 queries x its
// 100-point sub-slice via uniform (broadcast, conflict-free) LDS reads.
// Per block: 4 waves' keys min-reduce through LDS, one u64 per query to
// partial[slice][query]. No atomics, no init kernel.
// ---------------------------------------------------------------------------
__global__ __launch_bounds__(256, 4) void k_nn(
    const float* __restrict__ poses,      // [B,4,4]
    const float* __restrict__ wpts,       // [B,T,3]
    const float* __restrict__ boundary,   // [4,N]
    u64* __restrict__ partial,            // [BPQ][NQ]
    float* __restrict__ out)
{
    __shared__ f4 sh[PPB][2];             // pair-packed points, 6.4 KB
    __shared__ float qsh[3][QG];          // SoA queries, 3 KB (2-way free)
    __shared__ u64 red[4 * 256];          // cross-wave key reduce, 8 KB

    const int bx   = blockIdx.x;
    const int qg   = bx / BPQ;
    const int bsl  = bx - qg * BPQ;
    const int tid  = threadIdx.x;
    const int lane = tid & 63;
    const int wv   = tid >> 6;
    const int pbase = bsl * PTB;

    // out is consumed by k_epilogue (next dispatch) via atomicAdd; zero here.
    if (bx == 0 && tid == 0) out[0] = 0.0f;

    // ---- stage slice: (-2g, |g|^2) pair-packed (identical arithmetic) ----
    for (int pp = tid; pp < PPB; pp += 256) {
        const int n0 = pbase + 2 * pp;
        const f2 xx = *(const f2*)&boundary[n0];
        const f2 yy = *(const f2*)&boundary[N_ + n0];
        const f2 zz = *(const f2*)&boundary[2 * N_ + n0];
        const float x0 = xx.x, x1 = xx.y;
        const float y0 = yy.x, y1 = yy.y;
        const float z0 = zz.x, z1 = zz.y;
        f4 a = { -2.f * x0, -2.f * x1, -2.f * y0, -2.f * y1 };
        f4 b = { -2.f * z0, -2.f * z1,
                 x0 * x0 + y0 * y0 + z0 * z0,
                 x1 * x1 + y1 * y1 + z1 * z1 };
        sh[pp][0] = a;
        sh[pp][1] = b;
    }

    // ---- one query per thread: global waypoint q = R w + t -> LDS ----
    {
        const int i = qg * QG + tid;
        const int b = i / T_;
        const float* P = poses + b * 16;
        const float* W = wpts + i * 3;
        const float wx = W[0], wy = W[1], wz = W[2];
        qsh[0][tid] = P[0] * wx + P[1] * wy + P[2]  * wz + P[3];
        qsh[1][tid] = P[4] * wx + P[5] * wy + P[6]  * wz + P[7];
        qsh[2][tid] = P[8] * wx + P[9] * wy + P[10] * wz + P[11];
    }
    __syncthreads();

    // ---- 4 queries per lane, splats hoisted ----
    f2 vx[4], vy[4], vz[4];
#pragma unroll
    for (int s = 0; s < 4; ++s) {
        const int qi = s * 64 + lane;
        const float qxx = qsh[0][qi];
        const float qyy = qsh[1][qi];
        const float qzz = qsh[2][qi];
        vx[s] = (f2){ qxx, qxx };
        vy[s] = (f2){ qyy, qyy };
        vz[s] = (f2){ qzz, qzz };
    }

    const int prbase = wv * (PPB / 4);    // wave's pair base (wv*50)

    float best[4] = { FLT_MAX, FLT_MAX, FLT_MAX, FLT_MAX };
    int   bg[4]   = { 0, 0, 0, 0 };

#pragma unroll 5
    for (int g = 0; g < GPW; ++g) {
        const int pr = prbase + 2 * g;
        const f4 A0 = sh[pr][0],     B0 = sh[pr][1];
        const f4 A1 = sh[pr + 1][0], B1 = sh[pr + 1][1];
#pragma unroll
        for (int s = 0; s < 4; ++s) {
            const f2 e01 = edist2(A0, B0, vx[s], vy[s], vz[s]);
            const f2 e23 = edist2(A1, B1, vx[s], vy[s], vz[s]);
            const f2 m   = __builtin_elementwise_min(e01, e23);
            const float sc = fminf(m.x, m.y);
            bg[s]   = (sc < best[s]) ? g : bg[s];
            best[s] = fminf(sc, best[s]);
        }
    }

    // ---- resolve exact index inside winning group (identical FMA math) ----
#pragma unroll
    for (int s = 0; s < 4; ++s) {
        const int pr = prbase + 2 * bg[s];
        const f4 A0 = sh[pr][0],     B0 = sh[pr][1];
        const f4 A1 = sh[pr + 1][0], B1 = sh[pr + 1][1];
        const f2 e01 = edist2(A0, B0, vx[s], vy[s], vz[s]);
        const f2 e23 = edist2(A1, B1, vx[s], vy[s], vz[s]);
        const int base_i = pbase + wv * 100 + 4 * bg[s];
        const int li = (e01.x == best[s]) ? base_i
                     : (e01.y == best[s]) ? base_i + 1
                     : (e23.x == best[s]) ? base_i + 2 : base_i + 3;
        red[wv * 256 + s * 64 + lane] =
            ((u64)f32_sortable(best[s]) << 32) | (unsigned)li;
    }
    __syncthreads();

    // ---- cross-wave min (4 slices of the block) -> one u64 per query ----
    {
        const u64 a = red[tid],       b = red[256 + tid];
        const u64 c = red[512 + tid], d = red[768 + tid];
        const u64 m0 = a < b ? a : b;
        const u64 m1 = c < d ? c : d;
        partial[bsl * NQ + qg * QG + tid] = m0 < m1 ? m0 : m1;
    }
}

// ---------------------------------------------------------------------------
// Kernel 2: per query, min over the 50 slice-partials (coalesced), unpack
// winning index, global-frame epilogue: dots = (q - g) . n (rotation-
// invariant == reference's local-frame dot), ExpRelu, block-reduce, atomicAdd.
// Grid 50 x 128 for 2x CU coverage vs the old 25 x 256.
// ---------------------------------------------------------------------------
__global__ __launch_bounds__(EPI_T) void k_epilogue(
    const float* __restrict__ poses,
    const float* __restrict__ wpts,
    const float* __restrict__ boundary,   // [4,N]
    const float* __restrict__ bnorm,      // [3,N]
    const u64* __restrict__ partial,
    float* __restrict__ out)
{
    const int tid = threadIdx.x;
    const int i = blockIdx.x * EPI_T + tid;   // grid = 50 -> i in [0,6400)

    u64 best = ~0ull;
#pragma unroll 10
    for (int sl = 0; sl < BPQ; ++sl) {
        const u64 k = partial[sl * NQ + i];
        best = k < best ? k : best;
    }
    const int bi = (int)(unsigned)(best & 0xFFFFFFFFull);

    const int b = i / T_;
    const float* P = poses + b * 16;
    const float* W = wpts + i * 3;
    const float wx = W[0], wy = W[1], wz = W[2];
    const float qx = P[0] * wx + P[1] * wy + P[2]  * wz + P[3];
    const float qy = P[4] * wx + P[5] * wy + P[6]  * wz + P[7];
    const float qz = P[8] * wx + P[9] * wy + P[10] * wz + P[11];

    const float gx = boundary[bi], gy = boundary[N_ + bi], gz = boundary[2 * N_ + bi];
    const float nx = bnorm[bi],    ny = bnorm[N_ + bi],    nz = bnorm[2 * N_ + bi];

    const float dots = (qx - gx) * nx + (qy - gy) * ny + (qz - gz) * nz;
    // ExpRelu: alpha=1, beta=0.5; pre-scaled for the final mean
    float val = (dots > 0.0f) ? (dots + 1.0f) : expf(0.5f * dots);
    val *= (1.0f / (float)NQ);

    __shared__ float redf[EPI_T];
    redf[tid] = val;
    __syncthreads();
#pragma unroll
    for (int s = EPI_T / 2; s > 0; s >>= 1) {
        if (tid < s) redf[tid] += redf[tid + s];
        __syncthreads();
    }
    if (tid == 0) atomicAdd(out, redf[0]);
}

extern "C" void kernel_launch(void* const* d_in, const int* in_sizes, int n_in,
                              void* d_out, int out_size, void* d_ws, size_t ws_size,
                              hipStream_t stream) {
    const float* poses    = (const float*)d_in[0];
    const float* wpts     = (const float*)d_in[1];
    const float* boundary = (const float*)d_in[2];
    const float* bnorm    = (const float*)d_in[3];
    float* out = (float*)d_out;

    u64* partial = (u64*)((char*)d_ws + PART_OFF);

    k_nn<<<NQG * BPQ, 256, 0, stream>>>(poses, wpts, boundary, partial, out);
    k_epilogue<<<NQ / EPI_T, EPI_T, 0, stream>>>(
        poses, wpts, boundary, bnorm, partial, out);
}

// Round 4
// 77.905 us; speedup vs baseline: 1.2515x; 1.0129x over previous
//
#include <hip/hip_runtime.h>
#include <math.h>
#include <float.h>

#define B_ 64
#define T_ 100
#define N_ 20000
#define NQ (B_ * T_)              // 6400 queries
#define QG 256                    // queries per group = one block (4 per lane)
#define NQG (NQ / QG)             // 25 query groups
#define PTB 800                   // points per block (4 waves x 200)
#define PPB (PTB / 2)             // 400 point-pairs per block
#define BPQ (N_ / PTB)            // 25 point-slices = blocks per query group
#define DGPW 25                   // double-groups (8 points) per wave
#define EPI_T 64                  // k_epilogue block size (grid 100)

typedef float f2 __attribute__((ext_vector_type(2)));
typedef float f4 __attribute__((ext_vector_type(4)));
typedef unsigned long long u64;

// ws layout: u64 partial[BPQ][NQ]  (25 * 6400 * 8 = 1.28 MB)
// Every slot is written by its owning block -> no init pass, no atomics.
#define PART_OFF 0

// Map f32 -> u32 preserving < order for all finite values (incl. negatives).
__device__ __forceinline__ unsigned int f32_sortable(float f) {
    unsigned int u = __float_as_uint(f);
    return ((int)u >= 0) ? (u | 0x80000000u) : ~u;
}

// e = p2 - 2 q.g for a point-PAIR, FMA nesting identical to the verified
// kernels: fma(mx, qx, fma(my, qy, fma(mz, qz, p2)))
__device__ __forceinline__ f2 edist2(f4 A, f4 Bv, f2 vx, f2 vy, f2 vz) {
    f2 mx = { A.x,  A.y  }, my = { A.z,  A.w  };
    f2 mz = { Bv.x, Bv.y }, p2 = { Bv.z, Bv.w };
    return __builtin_elementwise_fma(mx, vx,
           __builtin_elementwise_fma(my, vy,
           __builtin_elementwise_fma(mz, vz, p2)));
}

// ---------------------------------------------------------------------------
// Kernel 1: NN. Block = (query-group of 256, point-slice of 800).
// Rigid transforms preserve distance, so the search runs in the global
// frame: q = R w + t, e = |g|^2 - 2 q.g (argmin-equivalent to |q-g|^2).
// Query sharing: each THREAD computes one query (bit-identical expression),
// publishes via SoA LDS; each LANE then owns 4 queries as hoisted splats.
// Each WAVE covers all 256 queries x its 200-point sub-slice via uniform
// (broadcast, conflict-free) LDS reads; argmin tracked per 8-point
// double-group (bookkeeping halved vs 4-point groups), resolved exactly
// afterwards with identical FMA math + lowest-index tie-break.
// Per block: 4 waves' keys min-reduce through LDS, one u64 per query to
// partial[slice][query]. No atomics, no init kernel.
// ---------------------------------------------------------------------------
__global__ __launch_bounds__(256, 4) void k_nn(
    const float* __restrict__ poses,      // [B,4,4]
    const float* __restrict__ wpts,       // [B,T,3]
    const float* __restrict__ boundary,   // [4,N]
    u64* __restrict__ partial,            // [BPQ][NQ]
    float* __restrict__ out)
{
    __shared__ f4 sh[PPB][2];             // pair-packed points, 12.8 KB
    __shared__ float qsh[3][QG];          // SoA queries, 3 KB
    __shared__ u64 red[4 * 256];          // cross-wave key reduce, 8 KB

    const int bx   = blockIdx.x;
    const int qg   = bx / BPQ;
    const int bsl  = bx - qg * BPQ;
    const int tid  = threadIdx.x;
    const int lane = tid & 63;
    const int wv   = tid >> 6;
    const int pbase = bsl * PTB;

    // out is consumed by k_epilogue (next dispatch) via atomicAdd; zero here.
    if (bx == 0 && tid == 0) out[0] = 0.0f;

    // ---- stage slice: (-2g, |g|^2) pair-packed (identical arithmetic) ----
    for (int pp = tid; pp < PPB; pp += 256) {
        const int n0 = pbase + 2 * pp;
        const f2 xx = *(const f2*)&boundary[n0];
        const f2 yy = *(const f2*)&boundary[N_ + n0];
        const f2 zz = *(const f2*)&boundary[2 * N_ + n0];
        const float x0 = xx.x, x1 = xx.y;
        const float y0 = yy.x, y1 = yy.y;
        const float z0 = zz.x, z1 = zz.y;
        f4 a = { -2.f * x0, -2.f * x1, -2.f * y0, -2.f * y1 };
        f4 b = { -2.f * z0, -2.f * z1,
                 x0 * x0 + y0 * y0 + z0 * z0,
                 x1 * x1 + y1 * y1 + z1 * z1 };
        sh[pp][0] = a;
        sh[pp][1] = b;
    }

    // ---- one query per thread: global waypoint q = R w + t -> LDS ----
    {
        const int i = qg * QG + tid;
        const int b = i / T_;
        const float* P = poses + b * 16;
        const float* W = wpts + i * 3;
        const float wx = W[0], wy = W[1], wz = W[2];
        qsh[0][tid] = P[0] * wx + P[1] * wy + P[2]  * wz + P[3];
        qsh[1][tid] = P[4] * wx + P[5] * wy + P[6]  * wz + P[7];
        qsh[2][tid] = P[8] * wx + P[9] * wy + P[10] * wz + P[11];
    }
    __syncthreads();

    // ---- 4 queries per lane, splats hoisted ----
    f2 vx[4], vy[4], vz[4];
#pragma unroll
    for (int s = 0; s < 4; ++s) {
        const int qi = s * 64 + lane;
        const float qxx = qsh[0][qi];
        const float qyy = qsh[1][qi];
        const float qzz = qsh[2][qi];
        vx[s] = (f2){ qxx, qxx };
        vy[s] = (f2){ qyy, qyy };
        vz[s] = (f2){ qzz, qzz };
    }

    const int prbase = wv * (PPB / 4);    // wave's pair base (wv*100)

    float best[4] = { FLT_MAX, FLT_MAX, FLT_MAX, FLT_MAX };
    int   bg[4]   = { 0, 0, 0, 0 };

#pragma unroll 5
    for (int g = 0; g < DGPW; ++g) {
        const int pr = prbase + 4 * g;
        const f4 A0 = sh[pr][0],     B0 = sh[pr][1];
        const f4 A1 = sh[pr + 1][0], B1 = sh[pr + 1][1];
        const f4 A2 = sh[pr + 2][0], B2 = sh[pr + 2][1];
        const f4 A3 = sh[pr + 3][0], B3 = sh[pr + 3][1];
#pragma unroll
        for (int s = 0; s < 4; ++s) {
            const f2 e01 = edist2(A0, B0, vx[s], vy[s], vz[s]);
            const f2 e23 = edist2(A1, B1, vx[s], vy[s], vz[s]);
            const f2 e45 = edist2(A2, B2, vx[s], vy[s], vz[s]);
            const f2 e67 = edist2(A3, B3, vx[s], vy[s], vz[s]);
            const f2 m0 = __builtin_elementwise_min(e01, e23);
            const f2 m1 = __builtin_elementwise_min(e45, e67);
            const f2 m  = __builtin_elementwise_min(m0, m1);
            const float sc = fminf(m.x, m.y);
            bg[s]   = (sc < best[s]) ? g : bg[s];
            best[s] = fminf(sc, best[s]);
        }
    }

    // ---- resolve exact index inside winning 8-group (identical FMA math) --
#pragma unroll
    for (int s = 0; s < 4; ++s) {
        const int pr = prbase + 4 * bg[s];
        const f4 A0 = sh[pr][0],     B0 = sh[pr][1];
        const f4 A1 = sh[pr + 1][0], B1 = sh[pr + 1][1];
        const f4 A2 = sh[pr + 2][0], B2 = sh[pr + 2][1];
        const f4 A3 = sh[pr + 3][0], B3 = sh[pr + 3][1];
        const f2 e01 = edist2(A0, B0, vx[s], vy[s], vz[s]);
        const f2 e23 = edist2(A1, B1, vx[s], vy[s], vz[s]);
        const f2 e45 = edist2(A2, B2, vx[s], vy[s], vz[s]);
        const f2 e67 = edist2(A3, B3, vx[s], vy[s], vz[s]);
        const int base_i = pbase + wv * 200 + 8 * bg[s];
        const int li = (e01.x == best[s]) ? base_i
                     : (e01.y == best[s]) ? base_i + 1
                     : (e23.x == best[s]) ? base_i + 2
                     : (e23.y == best[s]) ? base_i + 3
                     : (e45.x == best[s]) ? base_i + 4
                     : (e45.y == best[s]) ? base_i + 5
                     : (e67.x == best[s]) ? base_i + 6 : base_i + 7;
        red[wv * 256 + s * 64 + lane] =
            ((u64)f32_sortable(best[s]) << 32) | (unsigned)li;
    }
    __syncthreads();

    // ---- cross-wave min (4 slices of the block) -> one u64 per query ----
    {
        const u64 a = red[tid],       b = red[256 + tid];
        const u64 c = red[512 + tid], d = red[768 + tid];
        const u64 m0 = a < b ? a : b;
        const u64 m1 = c < d ? c : d;
        partial[bsl * NQ + qg * QG + tid] = m0 < m1 ? m0 : m1;
    }
}

// ---------------------------------------------------------------------------
// Kernel 2: per query, min over the 25 slice-partials (coalesced), unpack
// winning index, global-frame epilogue: dots = (q - g) . n (rotation-
// invariant == reference's local-frame dot), ExpRelu, block-reduce, atomicAdd.
// Grid 100 x 64 for wide CU coverage on the latency-sensitive gather.
// ---------------------------------------------------------------------------
__global__ __launch_bounds__(EPI_T) void k_epilogue(
    const float* __restrict__ poses,
    const float* __restrict__ wpts,
    const float* __restrict__ boundary,   // [4,N]
    const float* __restrict__ bnorm,      // [3,N]
    const u64* __restrict__ partial,
    float* __restrict__ out)
{
    const int tid = threadIdx.x;
    const int i = blockIdx.x * EPI_T + tid;   // grid = 100 -> i in [0,6400)

    u64 best = ~0ull;
#pragma unroll
    for (int sl = 0; sl < BPQ; ++sl) {
        const u64 k = partial[sl * NQ + i];
        best = k < best ? k : best;
    }
    const int bi = (int)(unsigned)(best & 0xFFFFFFFFull);

    const int b = i / T_;
    const float* P = poses + b * 16;
    const float* W = wpts + i * 3;
    const float wx = W[0], wy = W[1], wz = W[2];
    const float qx = P[0] * wx + P[1] * wy + P[2]  * wz + P[3];
    const float qy = P[4] * wx + P[5] * wy + P[6]  * wz + P[7];
    const float qz = P[8] * wx + P[9] * wy + P[10] * wz + P[11];

    const float gx = boundary[bi], gy = boundary[N_ + bi], gz = boundary[2 * N_ + bi];
    const float nx = bnorm[bi],    ny = bnorm[N_ + bi],    nz = bnorm[2 * N_ + bi];

    const float dots = (qx - gx) * nx + (qy - gy) * ny + (qz - gz) * nz;
    // ExpRelu: alpha=1, beta=0.5; pre-scaled for the final mean
    float val = (dots > 0.0f) ? (dots + 1.0f) : expf(0.5f * dots);
    val *= (1.0f / (float)NQ);

    __shared__ float redf[EPI_T];
    redf[tid] = val;
    __syncthreads();
#pragma unroll
    for (int s = EPI_T / 2; s > 0; s >>= 1) {
        if (tid < s) redf[tid] += redf[tid + s];
        __syncthreads();
    }
    if (tid == 0) atomicAdd(out, redf[0]);
}

extern "C" void kernel_launch(void* const* d_in, const int* in_sizes, int n_in,
                              void* d_out, int out_size, void* d_ws, size_t ws_size,
                              hipStream_t stream) {
    const float* poses    = (const float*)d_in[0];
    const float* wpts     = (const float*)d_in[1];
    const float* boundary = (const float*)d_in[2];
    const float* bnorm    = (const float*)d_in[3];
    float* out = (float*)d_out;

    u64* partial = (u64*)((char*)d_ws + PART_OFF);

    k_nn<<<NQG * BPQ, 256, 0, stream>>>(poses, wpts, boundary, partial, out);
    k_epilogue<<<NQ / EPI_T, EPI_T, 0, stream>>>(
        poses, wpts, boundary, bnorm, partial, out);
}